// Round 4
// baseline (131.414 us; speedup 1.0000x reference)
//
#include <hip/hip_runtime.h>
#include <hip/hip_fp16.h>
#include <stdint.h>

#define FREQS 10
#define DDIM 120   // 6 coords * 2 (sin,cos) * 10 freqs

typedef _Float16 half2_raw __attribute__((ext_vector_type(2)));

static __device__ __forceinline__ float fdot2f(__half2 a, __half2 b, float c) {
#if __has_builtin(__builtin_amdgcn_fdot2)
    return __builtin_amdgcn_fdot2(*(half2_raw*)&a, *(half2_raw*)&b, c, false);
#else
    float2 af = __half22float2(a), bf = __half22float2(b);
    return fmaf(af.x, bf.x, fmaf(af.y, bf.y, c));
#endif
}

// --- Kernel 1: convert W (fp32, [768][120]) to fp16 in workspace, 4 elems/thread ---
__global__ __launch_bounds__(256) void convert_w_f16(
    const float4* __restrict__ W4, uint2* __restrict__ Wh4, int n4)
{
    int i = blockIdx.x * blockDim.x + threadIdx.x;
    if (i < n4) {
        float4 v = W4[i];
        __half2 a = __floats2half2_rn(v.x, v.y);
        __half2 b = __floats2half2_rn(v.z, v.w);
        Wh4[i] = make_uint2(*(uint32_t*)&a, *(uint32_t*)&b);
    }
}

// --- Kernel 2: per-row gather + fdot2 dot products ---
// Enc layout matches W row order: element d = f*12 + t, t<6: sin(x_t * 2^f), t>=6: cos(x_{t-6} * 2^f).
// Packed half2 E[i] covers elements (2i, 2i+1); i = f*6 + p, p in {(s0,s1),(s2,s3),(s4,s5),(c0,c1),(c2,c3),(c4,c5)}.
__global__ __launch_bounds__(256, 4) void clnet_kernel(
    const float* __restrict__ X,
    const __half* __restrict__ Wh,       // [768][120] fp16
    const float* __restrict__ weights,   // [3, N]
    const int*   __restrict__ ids,       // [N, 3]
    float*       __restrict__ out,       // [N, 3]
    int N)
{
    int n = blockIdx.x * blockDim.x + threadIdx.x;
    if (n >= N) return;

    const float2* xp = reinterpret_cast<const float2*>(X + (size_t)n * 6);
    float2 a0 = xp[0], a1 = xp[1], a2 = xp[2];
    float x[6] = {a0.x, a0.y, a1.x, a1.y, a2.x, a2.y};

    bool mask = (x[0] == -1.0f) && (x[1] == -1.0f) && (x[2] == -1.0f);

    int   cid[3];
    float wk[3];
#pragma unroll
    for (int k = 0; k < 3; ++k) {
        cid[k] = ids[(size_t)n * 3 + k];
        wk[k]  = weights[(size_t)k * N + n];
    }

    // --- Positional encoding, packed fp16, via double-angle recurrence ---
    float s[6], c[6];
#pragma unroll
    for (int j = 0; j < 6; ++j) { s[j] = __sinf(x[j]); c[j] = __cosf(x[j]); }

    __half2 E[60];
#pragma unroll
    for (int f = 0; f < FREQS; ++f) {
        E[f * 6 + 0] = __floats2half2_rn(s[0], s[1]);
        E[f * 6 + 1] = __floats2half2_rn(s[2], s[3]);
        E[f * 6 + 2] = __floats2half2_rn(s[4], s[5]);
        E[f * 6 + 3] = __floats2half2_rn(c[0], c[1]);
        E[f * 6 + 4] = __floats2half2_rn(c[2], c[3]);
        E[f * 6 + 5] = __floats2half2_rn(c[4], c[5]);
        if (f < FREQS - 1) {
#pragma unroll
            for (int j = 0; j < 6; ++j) {
                float ts = s[j] + s[j];
                float sn = ts * c[j];
                float cn = fmaf(-ts, s[j], 1.0f);
                s[j] = sn; c[j] = cn;
            }
        }
    }

    float rgb[3] = {0.f, 0.f, 0.f};

#pragma unroll
    for (int k = 0; k < 3; ++k) {
        // cluster triple: 3 rows x 120 fp16 = 720 B, 16B-aligned (720*c % 16 == 0)
        const uint4* q = reinterpret_cast<const uint4*>(Wh + (size_t)cid[k] * (3 * DDIM));
        float acc[3] = {0.f, 0.f, 0.f};
#pragma unroll
        for (int r = 0; r < 3; ++r) {
#pragma unroll
            for (int ch = 0; ch < 15; ++ch) {      // 15 x uint4 = 60 dwords = 120 fp16 per row
                uint4 v = q[r * 15 + ch];
                uint32_t wd[4] = {v.x, v.y, v.z, v.w};
#pragma unroll
                for (int t = 0; t < 4; ++t) {
                    __half2 w2 = *reinterpret_cast<__half2*>(&wd[t]);
                    acc[r] = fdot2f(E[ch * 4 + t], w2, acc[r]);
                }
            }
        }
        rgb[0] = fmaf(wk[k], acc[0], rgb[0]);
        rgb[1] = fmaf(wk[k], acc[1], rgb[1]);
        rgb[2] = fmaf(wk[k], acc[2], rgb[2]);
    }

    if (mask) { rgb[0] = 0.f; rgb[1] = 0.f; rgb[2] = 0.f; }

    out[(size_t)n * 3 + 0] = rgb[0];
    out[(size_t)n * 3 + 1] = rgb[1];
    out[(size_t)n * 3 + 2] = rgb[2];
}

// --- fp32 fallback (ws too small): same structure, unpack E on the fly ---
__global__ __launch_bounds__(256) void clnet_kernel_f32(
    const float* __restrict__ X,
    const float* __restrict__ W,
    const float* __restrict__ weights,
    const int*   __restrict__ ids,
    float*       __restrict__ out,
    int N)
{
    int n = blockIdx.x * blockDim.x + threadIdx.x;
    if (n >= N) return;

    const float2* xp = reinterpret_cast<const float2*>(X + (size_t)n * 6);
    float2 a0 = xp[0], a1 = xp[1], a2 = xp[2];
    float x[6] = {a0.x, a0.y, a1.x, a1.y, a2.x, a2.y};
    bool mask = (x[0] == -1.0f) && (x[1] == -1.0f) && (x[2] == -1.0f);

    float s[6], c[6];
#pragma unroll
    for (int j = 0; j < 6; ++j) { s[j] = __sinf(x[j]); c[j] = __cosf(x[j]); }

    float E[DDIM];
#pragma unroll
    for (int f = 0; f < FREQS; ++f) {
#pragma unroll
        for (int j = 0; j < 6; ++j) { E[f * 12 + j] = s[j]; E[f * 12 + 6 + j] = c[j]; }
        if (f < FREQS - 1) {
#pragma unroll
            for (int j = 0; j < 6; ++j) {
                float ts = s[j] + s[j];
                float sn = ts * c[j];
                float cn = fmaf(-ts, s[j], 1.0f);
                s[j] = sn; c[j] = cn;
            }
        }
    }

    float rgb[3] = {0.f, 0.f, 0.f};
#pragma unroll
    for (int k = 0; k < 3; ++k) {
        int   cc = ids[(size_t)n * 3 + k];
        float wkk = weights[(size_t)k * N + n];
        const float4* wp = reinterpret_cast<const float4*>(W + (size_t)cc * (3 * DDIM));
        float acc[3] = {0.f, 0.f, 0.f};
#pragma unroll
        for (int ch = 0; ch < 90; ++ch) {
            float4 v = wp[ch];
            const int r = ch / 30, dbase = (ch % 30) * 4;
            acc[r] = fmaf(E[dbase + 0], v.x, acc[r]);
            acc[r] = fmaf(E[dbase + 1], v.y, acc[r]);
            acc[r] = fmaf(E[dbase + 2], v.z, acc[r]);
            acc[r] = fmaf(E[dbase + 3], v.w, acc[r]);
        }
        rgb[0] = fmaf(wkk, acc[0], rgb[0]);
        rgb[1] = fmaf(wkk, acc[1], rgb[1]);
        rgb[2] = fmaf(wkk, acc[2], rgb[2]);
    }

    if (mask) { rgb[0] = 0.f; rgb[1] = 0.f; rgb[2] = 0.f; }
    out[(size_t)n * 3 + 0] = rgb[0];
    out[(size_t)n * 3 + 1] = rgb[1];
    out[(size_t)n * 3 + 2] = rgb[2];
}

extern "C" void kernel_launch(void* const* d_in, const int* in_sizes, int n_in,
                              void* d_out, int out_size, void* d_ws, size_t ws_size,
                              hipStream_t stream)
{
    const float* X       = (const float*)d_in[0];
    const float* W       = (const float*)d_in[1];
    const float* weights = (const float*)d_in[2];
    const int*   ids     = (const int*)d_in[3];
    float*       out     = (float*)d_out;

    const int N      = in_sizes[0] / 6;     // 262144
    const int wElems = in_sizes[1];         // 768*120 = 92160

    const bool useF16 = (ws_size >= (size_t)wElems * sizeof(__half)) && (wElems % 4 == 0);

    const int blk = 256;
    if (useF16) {
        __half* Wh = (__half*)d_ws;
        int n4 = wElems / 4;
        convert_w_f16<<<(n4 + blk - 1) / blk, blk, 0, stream>>>(
            (const float4*)W, (uint2*)Wh, n4);
        clnet_kernel<<<(N + blk - 1) / blk, blk, 0, stream>>>(
            X, Wh, weights, ids, out, N);
    } else {
        clnet_kernel_f32<<<(N + blk - 1) / blk, blk, 0, stream>>>(
            X, W, weights, ids, out, N);
    }
}

// Round 6
// 90.845 us; speedup vs baseline: 1.4466x; 1.4466x over previous
//
#include <hip/hip_runtime.h>
#include <hip/hip_fp16.h>
#include <stdint.h>

#define FREQS 10
#define DDIM 120   // 6 coords * 2 (sin,cos) * 10 freqs

typedef _Float16 half2v __attribute__((ext_vector_type(2)));

static __device__ __forceinline__ uint32_t pk(float lo, float hi) {
    half2v h = {(_Float16)lo, (_Float16)hi};
    return *(uint32_t*)&h;
}

static __device__ __forceinline__ float fdot2f(uint32_t a, uint32_t b, float c) {
#if __has_builtin(__builtin_amdgcn_fdot2)
    return __builtin_amdgcn_fdot2(*(half2v*)&a, *(half2v*)&b, c, false);
#else
    half2v av = *(half2v*)&a, bv = *(half2v*)&b;
    return fmaf((float)av.x, (float)bv.x, fmaf((float)av.y, (float)bv.y, c));
#endif
}

// --- Convert W (fp32 [3C][120]) to fp16 chunked layout in d_ws ---
// cluster c, chunk ch in [0,CK): wrow = ch/RS, cc = ch%RS.
// cc<15: 8 fp16 of W[3c+wrow][cc*8 .. +7]. cc==15 (padded layout only): zeros.
template <int CK, int RS>
__global__ __launch_bounds__(256) void convert_w(
    const float* __restrict__ W, uint4* __restrict__ Wp, int nclusters)
{
    int idx = blockIdx.x * blockDim.x + threadIdx.x;
    if (idx >= nclusters * CK) return;
    int c = idx / CK, ch = idx % CK;
    int wrow = ch / RS, cc = ch % RS;
    uint4 d = make_uint4(0u, 0u, 0u, 0u);
    if (cc < 15) {
        const float* src = W + ((size_t)(3 * c + wrow) * DDIM + cc * 8);
        float4 a = *(const float4*)(src);
        float4 b = *(const float4*)(src + 4);
        d.x = pk(a.x, a.y); d.y = pk(a.z, a.w);
        d.z = pk(b.x, b.y); d.w = pk(b.z, b.w);
    }
    Wp[idx] = d;
}

// --- Quad-cooperative kernel: 4 lanes per row ---
// Lane l loads W chunks 4i+l of each row (quad covers one aligned 64B line/instr).
// Matching E chunk is 4i+l -> after LDS exchange each lane keeps E chunks
// {l, l+4, l+8, l+12} = 4 x uint4 = 16 VGPR. Row's E chunk 15 is ZEROED in LDS
// (padded W chunk 15 is zero, and 0*garbage could be NaN -- round-5 bug).
template <int CK, int RS>
__global__ __launch_bounds__(256, 4) void clnet_quad(
    const float* __restrict__ X,
    const uint4* __restrict__ Wp,       // [C][CK] 16B chunks, fp16
    const float* __restrict__ weights,  // [3, N]
    const int*   __restrict__ ids,      // [N, 3]
    float*       __restrict__ out,      // [N, 3]
    int N)
{
    __shared__ uint32_t elds[64 * 68];  // 64 rows x 272 B (17 chunks)

    const int tid = threadIdx.x;
    const int q = tid >> 2, l = tid & 3;
    const int n = blockIdx.x * 64 + q;
    const bool valid = (n < N);

    float x[6];
    bool mask = false;
    int cid[3] = {0, 0, 0};
    float wk[3] = {0.f, 0.f, 0.f};
    const unsigned eb = q * 68;  // dword base of this row's E region

    if (valid) {
        const float2* xp = (const float2*)(X + (size_t)n * 6);
        float2 a0 = xp[0], a1 = xp[1], a2 = xp[2];
        x[0] = a0.x; x[1] = a0.y; x[2] = a1.x; x[3] = a1.y; x[4] = a2.x; x[5] = a2.y;
        mask = (x[0] == -1.0f) && (x[1] == -1.0f) && (x[2] == -1.0f);
#pragma unroll
        for (int k = 0; k < 3; ++k) {
            cid[k] = ids[(size_t)n * 3 + k];
            wk[k]  = weights[(size_t)k * N + n];
        }

        // Cooperative enc: lane l computes freqs l, l+4, l+8 (f<10).
        // E element d = f*12 + t: t<6 -> sin(x_t*2^f), t>=6 -> cos(x_{t-6}*2^f).
#pragma unroll
        for (int fi = 0; fi < 3; ++fi) {
            int f = l + 4 * fi;
            if (f < FREQS) {
                float scale = (float)(1 << f);
                float s_[6], c_[6];
#pragma unroll
                for (int j = 0; j < 6; ++j) {
                    float v = x[j] * scale;
                    s_[j] = __sinf(v); c_[j] = __cosf(v);
                }
                unsigned o = eb + f * 6;
                *(uint2*)&elds[o + 0] = make_uint2(pk(s_[0], s_[1]), pk(s_[2], s_[3]));
                *(uint2*)&elds[o + 2] = make_uint2(pk(s_[4], s_[5]), pk(c_[0], c_[1]));
                *(uint2*)&elds[o + 4] = make_uint2(pk(c_[2], c_[3]), pk(c_[4], c_[5]));
            }
        }
        if (l == 3) {  // zero the pad chunk (dwords 60..63) - NaN guard
            *(uint4*)&elds[eb + 60] = make_uint4(0u, 0u, 0u, 0u);
        }
    }

    __syncthreads();   // all 256 threads reach this (no earlier returns)

    if (!valid) return;

    uint4 E[4];
#pragma unroll
    for (int j = 0; j < 4; ++j)
        E[j] = *(const uint4*)&elds[eb + (4 * j + l) * 4];  // chunk 4j+l (15 = zeros)

    float rgb[3] = {0.f, 0.f, 0.f};

#pragma unroll
    for (int k = 0; k < 3; ++k) {
        const uint4* base = Wp + (size_t)cid[k] * CK;
        float acc[3] = {0.f, 0.f, 0.f};
#pragma unroll
        for (int r = 0; r < 3; ++r) {
#pragma unroll
            for (int i = 0; i < 4; ++i) {
                // Unpadded layout (RS==15): chunk 15 doesn't exist -> skip i==3,l==3.
                if (RS == 16 || i < 3 || l < 3) {
                    uint4 wv = base[r * RS + 4 * i + l];
                    acc[r] = fdot2f(E[i].x, wv.x, acc[r]);
                    acc[r] = fdot2f(E[i].y, wv.y, acc[r]);
                    acc[r] = fdot2f(E[i].z, wv.z, acc[r]);
                    acc[r] = fdot2f(E[i].w, wv.w, acc[r]);
                }
            }
        }
        rgb[0] = fmaf(wk[k], acc[0], rgb[0]);
        rgb[1] = fmaf(wk[k], acc[1], rgb[1]);
        rgb[2] = fmaf(wk[k], acc[2], rgb[2]);
    }

    // Quad reduce (xor 1, xor 2 stay within the quad).
#pragma unroll
    for (int r = 0; r < 3; ++r) {
        rgb[r] += __shfl_xor(rgb[r], 1);
        rgb[r] += __shfl_xor(rgb[r], 2);
    }

    if (l < 3) {
        float v = (l == 0) ? rgb[0] : (l == 1) ? rgb[1] : rgb[2];
        if (mask) v = 0.f;
        out[(size_t)n * 3 + l] = v;
    }
}

// --- fp32 fallback (ws too small): known-correct per-thread path ---
__global__ __launch_bounds__(256) void clnet_kernel_f32(
    const float* __restrict__ X, const float* __restrict__ W,
    const float* __restrict__ weights, const int* __restrict__ ids,
    float* __restrict__ out, int N)
{
    int n = blockIdx.x * blockDim.x + threadIdx.x;
    if (n >= N) return;
    const float2* xp = (const float2*)(X + (size_t)n * 6);
    float2 a0 = xp[0], a1 = xp[1], a2 = xp[2];
    float x[6] = {a0.x, a0.y, a1.x, a1.y, a2.x, a2.y};
    bool mask = (x[0] == -1.0f) && (x[1] == -1.0f) && (x[2] == -1.0f);

    float E[DDIM];
#pragma unroll
    for (int f = 0; f < FREQS; ++f) {
        float scale = (float)(1 << f);
#pragma unroll
        for (int j = 0; j < 6; ++j) {
            float v = x[j] * scale;
            E[f * 12 + j] = __sinf(v); E[f * 12 + 6 + j] = __cosf(v);
        }
    }
    float rgb[3] = {0.f, 0.f, 0.f};
#pragma unroll
    for (int k = 0; k < 3; ++k) {
        int cc = ids[(size_t)n * 3 + k];
        float wkk = weights[(size_t)k * N + n];
        const float4* wp = (const float4*)(W + (size_t)cc * (3 * DDIM));
        float acc[3] = {0.f, 0.f, 0.f};
#pragma unroll
        for (int ch = 0; ch < 90; ++ch) {
            float4 v = wp[ch];
            const int r = ch / 30, dbase = (ch % 30) * 4;
            acc[r] = fmaf(E[dbase + 0], v.x, acc[r]);
            acc[r] = fmaf(E[dbase + 1], v.y, acc[r]);
            acc[r] = fmaf(E[dbase + 2], v.z, acc[r]);
            acc[r] = fmaf(E[dbase + 3], v.w, acc[r]);
        }
        rgb[0] = fmaf(wkk, acc[0], rgb[0]);
        rgb[1] = fmaf(wkk, acc[1], rgb[1]);
        rgb[2] = fmaf(wkk, acc[2], rgb[2]);
    }
    if (mask) { rgb[0] = 0.f; rgb[1] = 0.f; rgb[2] = 0.f; }
    out[(size_t)n * 3 + 0] = rgb[0];
    out[(size_t)n * 3 + 1] = rgb[1];
    out[(size_t)n * 3 + 2] = rgb[2];
}

extern "C" void kernel_launch(void* const* d_in, const int* in_sizes, int n_in,
                              void* d_out, int out_size, void* d_ws, size_t ws_size,
                              hipStream_t stream)
{
    const float* X       = (const float*)d_in[0];
    const float* W       = (const float*)d_in[1];
    const float* weights = (const float*)d_in[2];
    const int*   ids     = (const int*)d_in[3];
    float*       out     = (float*)d_out;

    const int N = in_sizes[0] / 6;             // 262144
    const int C = in_sizes[1] / (3 * DDIM);    // 256 clusters

    const size_t need48 = (size_t)C * 48 * 16; // 196608 B (padded rows, preferred)
    const size_t need45 = (size_t)C * 45 * 16; // 184320 B (unpadded fallback)

    const int blk = 256;
    const int gridMain = (N + 63) / 64;        // 4 lanes per row

    if (ws_size >= need48) {
        uint4* Wp = (uint4*)d_ws;
        int nchunk = C * 48;
        convert_w<48, 16><<<(nchunk + blk - 1) / blk, blk, 0, stream>>>(W, Wp, C);
        clnet_quad<48, 16><<<gridMain, blk, 0, stream>>>(X, Wp, weights, ids, out, N);
    } else if (ws_size >= need45) {
        uint4* Wp = (uint4*)d_ws;
        int nchunk = C * 45;
        convert_w<45, 15><<<(nchunk + blk - 1) / blk, blk, 0, stream>>>(W, Wp, C);
        clnet_quad<45, 15><<<gridMain, blk, 0, stream>>>(X, Wp, weights, ids, out, N);
    } else {
        clnet_kernel_f32<<<(N + blk - 1) / blk, blk, 0, stream>>>(
            X, W, weights, ids, out, N);
    }
}